// Round 7
// baseline (200.712 us; speedup 1.0000x reference)
//
#include <hip/hip_runtime.h>
#include <math.h>

#define NPIX 262144      // 512*512
#define T_B 4
#define T_C 20
#define KC 32            // k-chunks per job
#define CHUNKE (NPIX / KC)          // 8192 elements
#define ITERS (CHUNKE / (256 * 4))  // 8
#define NCOPY 8
#define GRAM_F 960       // 4b * 15 pair-blocks * 16
#define PART_F 1200      // + 4b * 20c * 3 slots

__device__ __forceinline__ float wave_red(float v) {
#pragma unroll
  for (int off = 32; off > 0; off >>= 1) v += __shfl_xor(v, off, 64);
  return v;
}
__device__ __forceinline__ int pb_idx(int I, int J) { return I * (11 - I) / 2 + (J - I); }
__device__ __forceinline__ float dot4(float4 a, float4 b, float acc) {
  return fmaf(a.x, b.x, fmaf(a.y, b.y, fmaf(a.z, b.z, fmaf(a.w, b.w, acc))));
}

// Barrier-free streaming gram+stats. Block = (chunk, job). Job: b(4) x
// {10 off-diag 4x4 pair-blocks + 5 diag(+stats) blocks}. Each block streams
// its 8192-element k-chunk: 8 float4 loads + 64 FMA per iter, no LDS staging,
// no __syncthreads in the main loop -> loads continuously in flight.
__global__ __launch_bounds__(256) void gs_kernel(const float* __restrict__ X,
                                                 const int* __restrict__ Y,
                                                 float* __restrict__ pw) {
  const int tid = threadIdx.x, w = tid >> 6, ln = tid & 63;
  const int chunk = blockIdx.x, job = blockIdx.y;
  const int b = job / 15, p = job % 15;
  const bool diag = (p >= 10);
  int I, J;
  if (diag) { I = J = p - 10; }
  else { int t = p; I = 0; while (t >= 4 - I) { t -= 4 - I; ++I; } J = I + 1 + t; }
  const int pb = pb_idx(I, J);

  const int koff = chunk * CHUNKE + (tid << 2);
  const float* xa = X + (size_t)(b * T_C + 4 * I) * NPIX + koff;
  const float* xb = X + (size_t)(b * T_C + 4 * J) * NPIX + koff;
  const int*   ya = Y + (size_t)(b * T_C + 4 * I) * NPIX + koff;

  float acc[16];
#pragma unroll
  for (int m = 0; m < 16; ++m) acc[m] = 0.f;
  float sxy[4] = {0, 0, 0, 0}, sy[4] = {0, 0, 0, 0}, sb[4] = {0, 0, 0, 0};

  if (!diag) {
    for (int it = 0; it < ITERS; ++it) {
      const int off = it * 1024;
      float4 av[4], bv[4];
#pragma unroll
      for (int r = 0; r < 4; ++r) av[r] = *(const float4*)(xa + (size_t)r * NPIX + off);
#pragma unroll
      for (int q = 0; q < 4; ++q) bv[q] = *(const float4*)(xb + (size_t)q * NPIX + off);
#pragma unroll
      for (int r = 0; r < 4; ++r)
#pragma unroll
        for (int q = 0; q < 4; ++q) acc[r * 4 + q] = dot4(av[r], bv[q], acc[r * 4 + q]);
    }
  } else if (I < 4) {  // diag block, channels 4I..4I+3 all < 16: stats need Y
    for (int it = 0; it < ITERS; ++it) {
      const int off = it * 1024;
      float4 av[4]; int4 yv[4];
#pragma unroll
      for (int r = 0; r < 4; ++r) av[r] = *(const float4*)(xa + (size_t)r * NPIX + off);
#pragma unroll
      for (int r = 0; r < 4; ++r) yv[r] = *(const int4*)(ya + (size_t)r * NPIX + off);
#pragma unroll
      for (int r = 0; r < 4; ++r) {
        const float xe[4] = {av[r].x, av[r].y, av[r].z, av[r].w};
        const int ye[4] = {yv[r].x, yv[r].y, yv[r].z, yv[r].w};
#pragma unroll
        for (int u = 0; u < 4; ++u) {
          const float fy = (float)ye[u];
          sxy[r] = fmaf(fy, xe[u], sxy[r]);
          sy[r] += fy;
          // y*log(x) + (1-y)*log1p(-x), y in {0,1} == log(y ? x : 1-x)
          sb[r] += __logf(ye[u] ? xe[u] : 1.f - xe[u]);
        }
      }
#pragma unroll
      for (int r = 0; r < 4; ++r)
#pragma unroll
        for (int q = 0; q < 4; ++q) acc[r * 4 + q] = dot4(av[r], av[q], acc[r * 4 + q]);
    }
  } else {  // diag block I==4: channels 16..19, stats = sum x only
    for (int it = 0; it < ITERS; ++it) {
      const int off = it * 1024;
      float4 av[4];
#pragma unroll
      for (int r = 0; r < 4; ++r) av[r] = *(const float4*)(xa + (size_t)r * NPIX + off);
#pragma unroll
      for (int r = 0; r < 4; ++r) sxy[r] += (av[r].x + av[r].y) + (av[r].z + av[r].w);
#pragma unroll
      for (int r = 0; r < 4; ++r)
#pragma unroll
        for (int q = 0; q < 4; ++q) acc[r * 4 + q] = dot4(av[r], av[q], acc[r * 4 + q]);
    }
  }

  // block reduce: wave_red per wave, cross-wave via tiny LDS, then spread atomics
  __shared__ float red[28][4];
#pragma unroll
  for (int m = 0; m < 16; ++m) {
    const float v = wave_red(acc[m]);
    if (ln == 0) red[m][w] = v;
  }
  if (diag) {
#pragma unroll
    for (int r = 0; r < 4; ++r) {
      float v = wave_red(sxy[r]); if (ln == 0) red[16 + r][w] = v;
      v = wave_red(sy[r]);        if (ln == 0) red[20 + r][w] = v;
      v = wave_red(sb[r]);        if (ln == 0) red[24 + r][w] = v;
    }
  }
  __syncthreads();
  const int nv = diag ? 28 : 16;
  if (tid < nv) {
    float* pc = pw + (chunk & (NCOPY - 1)) * PART_F;
    const float s = (red[tid][0] + red[tid][1]) + (red[tid][2] + red[tid][3]);
    if (tid < 16) {
      atomicAdd(&pc[(b * 15 + pb) * 16 + tid], s);
    } else {
      const int t = tid - 16, slot = t >> 2, r = t & 3;
      atomicAdd(&pc[GRAM_F + (b * T_C + 4 * I + r) * 3 + slot], s);
    }
  }
}

// ---------------- finalize: sum 8 copies, compute 4 scalars ----------------
__global__ __launch_bounds__(64) void finalize_kernel(const float* __restrict__ pw,
                                                      float* __restrict__ out) {
  __shared__ float red[PART_F];
  const int ln = threadIdx.x;
  for (int o = ln; o < PART_F; o += 64) {
    float s = 0.f;
#pragma unroll
    for (int c8 = 0; c8 < NCOPY; ++c8) s += pw[c8 * PART_F + o];
    red[o] = s;
  }
  __syncthreads();
  const float invBN = 1.f / (4.f * 262144.f);

  // loss3
  float l3p = 0.f;
  for (int ij = ln; ij < 400; ij += 64) {
    const int i = ij / 20, j = ij % 20;
    if (i == j) continue;
    const int Ii = i >> 2, ri = i & 3, Jj = j >> 2, rj = j & 3;
    float sum = 0.f;
#pragma unroll
    for (int b = 0; b < 4; ++b) {
      float g = (Ii <= Jj) ? red[(b * 15 + pb_idx(Ii, Jj)) * 16 + ri * 4 + rj]
                           : red[(b * 15 + pb_idx(Jj, Ii)) * 16 + rj * 4 + ri];
      float si = red[(b * 15 + pb_idx(Ii, Ii)) * 16 + ri * 5];
      float sj = red[(b * 15 + pb_idx(Jj, Jj)) * 16 + rj * 5];
      sum += (g + 1.f) / (si + sj + 1.f);
    }
    l3p += sum * 0.25f;
  }
  const float l3 = wave_red(l3p) / 380.f;

  // loss1: dice + bce, c<16
  float l1p = 0.f;
  if (ln < 16) {
    const int c = ln, Ic = c >> 2, rc = c & 3;
    float d = 0.f, bsum = 0.f;
#pragma unroll
    for (int b = 0; b < 4; ++b) {
      float num = red[GRAM_F + (b * T_C + c) * 3 + 0] + 1.f;
      float s = red[(b * 15 + pb_idx(Ic, Ic)) * 16 + rc * 5];      // sum x^2 (gram diag)
      float den = s + red[GRAM_F + (b * T_C + c) * 3 + 1] + 1.f;   // + sum y
      d += 1.f - num / den;
      bsum += red[GRAM_F + (b * T_C + c) * 3 + 2];
    }
    l1p = d * 0.25f - bsum * invBN;
  }
  const float l1 = wave_red(l1p) * (1.f / 16.f);

  // loss2: c>=16
  float l2p = 0.f;
  if (ln >= 16 && ln < 20) {
    float s = 0.f;
#pragma unroll
    for (int b = 0; b < 4; ++b) s += red[GRAM_F + (b * T_C + ln) * 3 + 0];
    float m = s * invBN;
    float vv = fminf(fmaxf(m * 50.f, 0.f), 1.f);
    l2p = -logf(vv);
  }
  const float l2 = wave_red(l2p) * 0.25f;

  if (ln == 0) {
    out[1] = l1; out[2] = l2; out[3] = l3;
    out[0] = 0.1f * (l1 + l2 + l3);
  }
}

extern "C" void kernel_launch(void* const* d_in, const int* in_sizes, int n_in,
                              void* d_out, int out_size, void* d_ws, size_t ws_size,
                              hipStream_t stream) {
  const float* X = (const float*)d_in[0];
  const int* Y = (const int*)d_in[1];
  float* ws = (float*)d_ws;
  float* out = (float*)d_out;

  hipMemsetAsync(ws, 0, NCOPY * PART_F * sizeof(float), stream);
  gs_kernel<<<dim3(KC, 60), 256, 0, stream>>>(X, Y, ws);
  finalize_kernel<<<1, 64, 0, stream>>>(ws, out);
}